// Round 1
// baseline (500.991 us; speedup 1.0000x reference)
//
#include <hip/hip_runtime.h>
#include <stdint.h>

typedef unsigned short u16;
#define DEVFN static __device__ __forceinline__

constexpr int   kB   = 64;
constexpr int   kN   = 4096;
constexpr float kEPS = 1e-8f;
constexpr float kLNE = 1e-5f;
constexpr float kKSC = 0.08838834764831845f;  // SLOT^-0.5
constexpr float kISC = 0.125f;                 // I^-0.5

DEVFN float bf2f(uint32_t u) { union { uint32_t u; float f; } x; x.u = u << 16; return x.f; }
DEVFN u16 f2bf(float f) {
    union { float f; uint32_t u; } x; x.f = f;
    uint32_t r = (x.u + 0x7fffu + ((x.u >> 16) & 1u)) >> 16;
    return (u16)r;
}
DEVFN void unpack8(uint4 p, float* d) {
    d[0] = bf2f(p.x & 0xffffu); d[1] = bf2f(p.x >> 16);
    d[2] = bf2f(p.y & 0xffffu); d[3] = bf2f(p.y >> 16);
    d[4] = bf2f(p.z & 0xffffu); d[5] = bf2f(p.z >> 16);
    d[6] = bf2f(p.w & 0xffffu); d[7] = bf2f(p.w >> 16);
}
DEVFN float sigf(float x) { return 1.0f / (1.0f + __expf(-x)); }

// ---------------- A0: init slots_ext / logits_pi ----------------
__global__ void kinit(const float* __restrict__ ext_mu, const float* __restrict__ ext_ls,
                      const float* __restrict__ int_mu, const float* __restrict__ int_ls,
                      const float* __restrict__ ext_noise, const float* __restrict__ int_noise,
                      float* __restrict__ sext, float* __restrict__ lpi)
{
    int t = blockIdx.x * 256 + threadIdx.x;  // 32768 threads
    int e = t & 63;
    sext[t] = ext_mu[e] + __expf(ext_ls[e]) * ext_noise[t];
    lpi[t]  = int_mu[e] + __expf(int_ls[e]) * int_noise[t];
}

// ---------------- A2: Wcomb = [Wk*scale | Wv]; p = LN(protos)@Wp; pT ----------------
__global__ void kprep(const float* __restrict__ Wk, const float* __restrict__ Wv,
                      const float* __restrict__ protos, const float* __restrict__ Wp,
                      const float* __restrict__ lpg, const float* __restrict__ lpb,
                      float* __restrict__ Wcomb, float* __restrict__ p, float* __restrict__ pT)
{
    __shared__ float pl[64][65];
    __shared__ float mS[64], sS[64];
    int t = threadIdx.x;  // 256
    for (int idx = t; idx < 128 * 256; idx += 256) {
        int k = idx >> 8, c = idx & 255;
        Wcomb[idx] = (c < 128) ? Wk[k * 128 + c] * kKSC : Wv[k * 128 + (c - 128)];
    }
    for (int idx = t; idx < 64 * 64; idx += 256) pl[idx >> 6][idx & 63] = protos[idx];
    __syncthreads();
    if (t < 64) {
        float sm = 0.f, sq = 0.f;
        for (int k = 0; k < 64; ++k) { float v = pl[t][k]; sm += v; sq += v * v; }
        float m = sm * (1.0f / 64.0f);
        float var = sq * (1.0f / 64.0f) - m * m;
        mS[t] = m; sS[t] = rsqrtf(var + kLNE);
    }
    __syncthreads();
    for (int idx = t; idx < 64 * 64; idx += 256) {
        int r = idx >> 6, c = idx & 63;
        pl[r][c] = (pl[r][c] - mS[r]) * sS[r] * lpg[c] + lpb[c];
    }
    __syncthreads();
    for (int idx = t; idx < 64 * 64; idx += 256) {
        int r = idx >> 6, c = idx & 63;
        float acc = 0.f;
        for (int k = 0; k < 64; ++k) acc += pl[r][k] * Wp[k * 64 + c];
        p[r * 64 + c] = acc;
        pT[c * 64 + r] = acc;
    }
}

// ---------------- A1: x=LN(inputs); kk=x@Wk*s (bf16), vv=x@Wv (bf16), vvsum partials ----------------
__global__ __launch_bounds__(256) void kmain(const float* __restrict__ inputs,
                                             const float* __restrict__ Wcomb,
                                             const float* __restrict__ lng, const float* __restrict__ lnb,
                                             u16* __restrict__ kk, u16* __restrict__ vv,
                                             float* __restrict__ vpart)
{
    __shared__ float xT[128][68];   // [k][row], 64 rows per block
    __shared__ float ps[4][64], pq[4][64];
    __shared__ float mS[64], sS[64];
    const int t = threadIdx.x;
    const int blk = blockIdx.x;           // 4096 blocks
    const int b = blk >> 6;               // 64 blocks per batch
    const int n0 = (blk & 63) * 64;
    const float* inp = inputs + ((size_t)(b * kN + n0)) * 128;

    #pragma unroll
    for (int j = 0; j < 8; ++j) {
        int f4 = t + j * 256;             // 2048 float4 = 64x128
        int r = f4 >> 5, c4 = (f4 & 31) * 4;
        float4 v = ((const float4*)inp)[f4];
        xT[c4 + 0][r] = v.x; xT[c4 + 1][r] = v.y; xT[c4 + 2][r] = v.z; xT[c4 + 3][r] = v.w;
    }
    __syncthreads();
    {
        int r = t & 63, kg = t >> 6;
        float sm = 0.f, sq = 0.f;
        for (int k2 = 0; k2 < 32; ++k2) {
            float v = xT[kg * 32 + k2][r];
            sm += v; sq += v * v;
        }
        ps[kg][r] = sm; pq[kg][r] = sq;
    }
    __syncthreads();
    if (t < 64) {
        float sm = ps[0][t] + ps[1][t] + ps[2][t] + ps[3][t];
        float sq = pq[0][t] + pq[1][t] + pq[2][t] + pq[3][t];
        float m = sm * (1.0f / 128.0f);
        float var = sq * (1.0f / 128.0f) - m * m;
        mS[t] = m; sS[t] = rsqrtf(var + kLNE);
    }
    __syncthreads();
    {
        int r = t & 63, kg = t >> 6;
        float m = mS[r], sc = sS[r];
        for (int k2 = 0; k2 < 32; ++k2) {
            int k = kg * 32 + k2;
            xT[k][r] = (xT[k][r] - m) * sc * lng[k] + lnb[k];
        }
    }
    __syncthreads();

    const int cset = t & 31, rg = t >> 5;
    float acc[8][8];
    #pragma unroll
    for (int j = 0; j < 8; ++j)
        #pragma unroll
        for (int rr = 0; rr < 8; ++rr) acc[j][rr] = 0.f;

    const float4* W4 = (const float4*)Wcomb;
    const float4* x4 = (const float4*)(&xT[0][0]);
    #pragma unroll 2
    for (int k = 0; k < 128; ++k) {
        float4 wA = W4[k * 64 + (cset << 1)];
        float4 wB = W4[k * 64 + (cset << 1) + 1];
        float4 x0 = x4[k * 17 + (rg << 1)];
        float4 x1 = x4[k * 17 + (rg << 1) + 1];
        float wv[8] = { wA.x, wA.y, wA.z, wA.w, wB.x, wB.y, wB.z, wB.w };
        float xv[8] = { x0.x, x0.y, x0.z, x0.w, x1.x, x1.y, x1.z, x1.w };
        #pragma unroll
        for (int j = 0; j < 8; ++j)
            #pragma unroll
            for (int rr = 0; rr < 8; ++rr)
                acc[j][rr] = fmaf(xv[rr], wv[j], acc[j][rr]);
    }
    __syncthreads();   // xT reads done; its LDS is reused below

    const bool isv = (cset >= 16);
    u16* outp = (isv ? vv : kk) + ((size_t)(b * kN + n0 + rg * 8)) * 128 + (cset & 15) * 8;
    #pragma unroll
    for (int rr = 0; rr < 8; ++rr) {
        uint4 pko;
        pko.x = (uint32_t)f2bf(acc[0][rr]) | ((uint32_t)f2bf(acc[1][rr]) << 16);
        pko.y = (uint32_t)f2bf(acc[2][rr]) | ((uint32_t)f2bf(acc[3][rr]) << 16);
        pko.z = (uint32_t)f2bf(acc[4][rr]) | ((uint32_t)f2bf(acc[5][rr]) << 16);
        pko.w = (uint32_t)f2bf(acc[6][rr]) | ((uint32_t)f2bf(acc[7][rr]) << 16);
        *((uint4*)(outp + (size_t)rr * 128)) = pko;
    }
    // vvsum partials: reduce 8 row-groups via reused xT LDS
    float* vred = &xT[0][0];
    if (isv) {
        #pragma unroll
        for (int j = 0; j < 8; ++j) {
            float s = 0.f;
            #pragma unroll
            for (int rr = 0; rr < 8; ++rr) s += acc[j][rr];
            vred[rg * 128 + (cset & 15) * 8 + j] = s;
        }
    }
    __syncthreads();
    if (t < 128) {
        float s = 0.f;
        #pragma unroll
        for (int rgi = 0; rgi < 8; ++rgi) s += vred[rgi * 128 + t];
        vpart[(size_t)blk * 128 + t] = s;
    }
}

// ---------------- A3: reduce vvsum partials ----------------
__global__ void kvvsum(const float* __restrict__ part, float* __restrict__ vvsum)
{
    int t = blockIdx.x * 256 + threadIdx.x;  // 8192
    int b = t >> 7, c = t & 127;
    float s = 0.f;
    const float* pp = part + (size_t)b * 64 * 128 + c;
    for (int nb = 0; nb < 64; ++nb) s += pp[nb * 128];
    vvsum[t] = s;
}

// ---------------- K1: pi softmax, slots_int, slots build, q ----------------
__global__ void kslots(const float* __restrict__ lpi, const float* __restrict__ gum,
                       const void* __restrict__ taup,
                       const float* __restrict__ p,
                       const float* __restrict__ sbck, const float* __restrict__ sext,
                       const float* __restrict__ Wq,
                       float* __restrict__ sint, float* __restrict__ q)
{
    __shared__ float piL[64];
    __shared__ float sv[128];
    const int bs = blockIdx.x;     // 512
    const int b = bs >> 3, s = bs & 7;
    const int t = threadIdx.x;     // 128
    float inv_tau = 1.0f;
    {
        int iv = *(const int*)taup;
        if (iv > 0 && iv < 1000000) inv_tau = 1.0f / (float)iv;
        else {
            float fv = *(const float*)taup;
            if (fv > 1e-6f && fv < 1e6f) inv_tau = 1.0f / fv;
        }
    }
    if (t < 64) {
        float l = (lpi[bs * 64 + t] + gum[bs * 64 + t]) * inv_tau;
        float m = l;
        #pragma unroll
        for (int d = 32; d >= 1; d >>= 1) m = fmaxf(m, __shfl_xor(m, d));
        float e = __expf(l - m);
        float sm = e;
        #pragma unroll
        for (int d = 32; d >= 1; d >>= 1) sm += __shfl_xor(sm, d);
        piL[t] = e / sm;
    }
    __syncthreads();
    if (t < 64) {
        float acc = 0.f;
        for (int c = 0; c < 64; ++c) acc += piL[c] * p[c * 64 + t];
        sint[bs * 64 + t] = acc;
        if (s == 0) {
            sv[t]      = sbck[b * 128 + t];
            sv[64 + t] = sbck[b * 128 + 64 + t];
        } else {
            sv[t]      = acc;
            sv[64 + t] = sext[bs * 64 + t];
        }
    }
    __syncthreads();
    {
        float acc = 0.f;
        for (int k = 0; k < 128; ++k) acc += sv[k] * Wq[k * 128 + t];
        q[bs * 128 + t] = acc;
    }
}

// ---------------- K2: attention pass (logits, softmax, attn_vis, update partials) ----------------
__global__ __launch_bounds__(256) void kattn(const u16* __restrict__ kk, const u16* __restrict__ vv,
                                             const float* __restrict__ q,
                                             float* __restrict__ attn_out,
                                             float* __restrict__ pu, float* __restrict__ pcs)
{
    __shared__ float qL[8][132];
    __shared__ float kkL[32][132];
    __shared__ float vvL[32][132];
    __shared__ float aL[32 * 8];
    const int t = threadIdx.x;
    const int blk = blockIdx.x;     // 1024
    const int b = blk >> 4;
    const int nb = blk & 15;        // 256 rows per block
    {
        int idx = t * 4;
        float4 v = *((const float4*)(q + (size_t)b * 1024 + idx));
        *((float4*)&qL[idx >> 7][idx & 127]) = v;
    }
    const int r8 = t >> 3, sl = t & 7;
    const int s2 = t >> 5, dg = t & 31;
    float acc0 = 0.f, acc1 = 0.f, acc2 = 0.f, acc3 = 0.f, cs = 0.f;
    __syncthreads();
    for (int ch = 0; ch < 8; ++ch) {
        const int nbase = nb * 256 + ch * 32;
        const u16* kp = kk + ((size_t)(b * kN + nbase)) * 128;
        const u16* vp = vv + ((size_t)(b * kN + nbase)) * 128;
        #pragma unroll
        for (int rnd = 0; rnd < 2; ++rnd) {
            const int flat = (t + rnd * 256) * 8;
            const int rr = flat >> 7, c0 = flat & 127;
            uint4 pk = *((const uint4*)(kp + flat));
            uint4 pv = *((const uint4*)(vp + flat));
            float fk[8], fvv[8];
            unpack8(pk, fk); unpack8(pv, fvv);
            *((float4*)&kkL[rr][c0])     = make_float4(fk[0], fk[1], fk[2], fk[3]);
            *((float4*)&kkL[rr][c0 + 4]) = make_float4(fk[4], fk[5], fk[6], fk[7]);
            *((float4*)&vvL[rr][c0])     = make_float4(fvv[0], fvv[1], fvv[2], fvv[3]);
            *((float4*)&vvL[rr][c0 + 4]) = make_float4(fvv[4], fvv[5], fvv[6], fvv[7]);
        }
        __syncthreads();
        float lg = 0.f;
        {
            const float4* kr = (const float4*)&kkL[r8][0];
            const float4* qr = (const float4*)&qL[sl][0];
            #pragma unroll 8
            for (int k4 = 0; k4 < 32; ++k4) {
                float4 kx = kr[k4], qx = qr[k4];
                lg = fmaf(kx.x, qx.x, lg); lg = fmaf(kx.y, qx.y, lg);
                lg = fmaf(kx.z, qx.z, lg); lg = fmaf(kx.w, qx.w, lg);
            }
        }
        float m = lg;
        m = fmaxf(m, __shfl_xor(m, 1)); m = fmaxf(m, __shfl_xor(m, 2)); m = fmaxf(m, __shfl_xor(m, 4));
        float e = __expf(lg - m);
        float sm = e;
        sm += __shfl_xor(sm, 1); sm += __shfl_xor(sm, 2); sm += __shfl_xor(sm, 4);
        float av = e / sm;
        attn_out[((size_t)(b * kN + nbase + r8)) * 8 + sl] = av;
        aL[r8 * 8 + sl] = av;
        __syncthreads();
        #pragma unroll 4
        for (int rr = 0; rr < 32; ++rr) {
            float aw = aL[rr * 8 + s2];
            float4 v = *((const float4*)&vvL[rr][dg * 4]);
            acc0 = fmaf(aw, v.x, acc0); acc1 = fmaf(aw, v.y, acc1);
            acc2 = fmaf(aw, v.z, acc2); acc3 = fmaf(aw, v.w, acc3);
            cs += aw;
        }
        __syncthreads();
    }
    *((float4*)(pu + (size_t)blk * 1024 + s2 * 128 + dg * 4)) = make_float4(acc0, acc1, acc2, acc3);
    if (dg == 0) pcs[blk * 8 + s2] = cs;
}

// ---------------- K3: updates, GRUs, MLPs, new logits; final outputs ----------------
__global__ __launch_bounds__(256) void kupdate(
    const float* __restrict__ pu, const float* __restrict__ pcs,
    const float* __restrict__ vvsum, const float* __restrict__ sint,
    float* __restrict__ sext, float* __restrict__ lpi,
    const float* __restrict__ giWih, const float* __restrict__ giWhh,
    const float* __restrict__ gibih, const float* __restrict__ gibhh,
    const float* __restrict__ geWih, const float* __restrict__ geWhh,
    const float* __restrict__ gebih, const float* __restrict__ gebhh,
    const float* __restrict__ miW1, const float* __restrict__ mib1,
    const float* __restrict__ miW2, const float* __restrict__ mib2,
    const float* __restrict__ meW1, const float* __restrict__ meb1,
    const float* __restrict__ meW2, const float* __restrict__ meb2,
    const float* __restrict__ lmig, const float* __restrict__ lmib,
    const float* __restrict__ lmeg, const float* __restrict__ lmeb,
    const float* __restrict__ pT, float* __restrict__ out, const int last)
{
    __shared__ float uL[128], hA[64], hB[64];
    __shared__ float g1[192], g2[192];
    __shared__ float tmp[256];
    __shared__ float outE[64], outI[64];
    const int bs = blockIdx.x;   // 512
    const int b = bs >> 3, s = bs & 7;
    const int t = threadIdx.x;   // 256

    if (t < 128) {
        float num = 0.f;
        for (int nb = 0; nb < 16; ++nb) num += pu[((size_t)((b * 16 + nb) * 8 + s)) * 128 + t];
        float den = 4096.0f * kEPS;
        for (int nb = 0; nb < 16; ++nb) den += pcs[(b * 16 + nb) * 8 + s];
        uL[t] = (num + kEPS * vvsum[b * 128 + t]) / den;
    } else if (t < 192) {
        hA[t - 128] = sext[bs * 64 + (t - 128)];
    } else {
        hB[t - 192] = sint[bs * 64 + (t - 192)];
    }
    __syncthreads();
    // GRU ext: x = uL[64..127], h = hA
    if (t < 192) {
        float a = gebih[t], bb = gebhh[t];
        for (int k = 0; k < 64; ++k) {
            a  = fmaf(uL[64 + k], geWih[k * 192 + t], a);
            bb = fmaf(hA[k],      geWhh[k * 192 + t], bb);
        }
        g1[t] = a; g2[t] = bb;
    }
    __syncthreads();
    if (t < 64) {
        float r = sigf(g1[t] + g2[t]);
        float z = sigf(g1[64 + t] + g2[64 + t]);
        float nn = tanhf(g1[128 + t] + r * g2[128 + t]);
        outE[t] = (1.0f - z) * nn + z * hA[t];
    }
    __syncthreads();
    // GRU int: x = uL[0..63], h = hB
    if (t < 192) {
        float a = gibih[t], bb = gibhh[t];
        for (int k = 0; k < 64; ++k) {
            a  = fmaf(uL[k], giWih[k * 192 + t], a);
            bb = fmaf(hB[k], giWhh[k * 192 + t], bb);
        }
        g1[t] = a; g2[t] = bb;
    }
    __syncthreads();
    if (t < 64) {
        float r = sigf(g1[t] + g2[t]);
        float z = sigf(g1[64 + t] + g2[64 + t]);
        float nn = tanhf(g1[128 + t] + r * g2[128 + t]);
        outI[t] = (1.0f - z) * nn + z * hB[t];
    }
    __syncthreads();
    if (!last) {
        // MLP ext
        if (t < 64) {
            float v = outE[t];
            float sm = v, sq = v * v;
            #pragma unroll
            for (int d = 32; d >= 1; d >>= 1) { sm += __shfl_xor(sm, d); sq += __shfl_xor(sq, d); }
            float m = sm * (1.0f / 64.0f), var = sq * (1.0f / 64.0f) - m * m;
            g1[t] = (v - m) * rsqrtf(var + kLNE) * lmeg[t] + lmeb[t];
        }
        __syncthreads();
        {
            float a = meb1[t];
            for (int k = 0; k < 64; ++k) a = fmaf(g1[k], meW1[k * 256 + t], a);
            tmp[t] = fmaxf(a, 0.0f);
        }
        __syncthreads();
        if (t < 64) {
            float o = meb2[t];
            for (int j = 0; j < 256; ++j) o = fmaf(tmp[j], meW2[j * 64 + t], o);
            outE[t] += o;
        }
        __syncthreads();
        // MLP int
        if (t < 64) {
            float v = outI[t];
            float sm = v, sq = v * v;
            #pragma unroll
            for (int d = 32; d >= 1; d >>= 1) { sm += __shfl_xor(sm, d); sq += __shfl_xor(sq, d); }
            float m = sm * (1.0f / 64.0f), var = sq * (1.0f / 64.0f) - m * m;
            g1[t] = (v - m) * rsqrtf(var + kLNE) * lmig[t] + lmib[t];
        }
        __syncthreads();
        {
            float a = mib1[t];
            for (int k = 0; k < 64; ++k) a = fmaf(g1[k], miW1[k * 256 + t], a);
            tmp[t] = fmaxf(a, 0.0f);
        }
        __syncthreads();
        if (t < 64) {
            float o = mib2[t];
            for (int j = 0; j < 256; ++j) o = fmaf(tmp[j], miW2[j * 64 + t], o);
            outI[t] += o;
        }
        __syncthreads();
    }
    if (t < 64) {
        float lg = 0.f;
        for (int k = 0; k < 64; ++k) lg = fmaf(outI[k], pT[k * 64 + t], lg);
        lg *= kISC;
        lpi[bs * 64 + t] = lg;
        if (last && s > 0) out[28672 + (b * 7 + (s - 1)) * 64 + t] = lg;
    } else if (t < 128) {
        int c = t - 64;
        float v = outE[c];
        sext[bs * 64 + c] = v;
        if (last && s > 0) out[(b * 7 + (s - 1)) * 64 + c] = v;
    }
}

extern "C" void kernel_launch(void* const* d_in, const int* in_sizes, int n_in,
                              void* d_out, int out_size, void* d_ws, size_t ws_size,
                              hipStream_t stream)
{
    (void)in_sizes; (void)n_in; (void)out_size; (void)ws_size;
    const float* slots_bck = (const float*)d_in[0];
    const float* inputs    = (const float*)d_in[1];
    const float* protos    = (const float*)d_in[2];
    const float* ext_noise = (const float*)d_in[3];
    const float* int_noise = (const float*)d_in[4];
    const float* gumbel    = (const float*)d_in[5];
    const void*  taup      = d_in[6];
    const float* ext_mu    = (const float*)d_in[7];
    const float* ext_ls    = (const float*)d_in[8];
    const float* int_mu    = (const float*)d_in[9];
    const float* int_ls    = (const float*)d_in[10];
    const float* ln_in_g   = (const float*)d_in[11];
    const float* ln_in_b   = (const float*)d_in[12];
    const float* ln_p_g    = (const float*)d_in[13];
    const float* ln_p_b    = (const float*)d_in[14];
    const float* ln_mi_g   = (const float*)d_in[15];
    const float* ln_mi_b   = (const float*)d_in[16];
    const float* ln_me_g   = (const float*)d_in[17];
    const float* ln_me_b   = (const float*)d_in[18];
    const float* Wq        = (const float*)d_in[19];
    const float* Wk        = (const float*)d_in[20];
    const float* Wv        = (const float*)d_in[21];
    const float* Wp        = (const float*)d_in[22];
    const float* giWih     = (const float*)d_in[23];
    const float* giWhh     = (const float*)d_in[24];
    const float* gibih     = (const float*)d_in[25];
    const float* gibhh     = (const float*)d_in[26];
    const float* geWih     = (const float*)d_in[27];
    const float* geWhh     = (const float*)d_in[28];
    const float* gebih     = (const float*)d_in[29];
    const float* gebhh     = (const float*)d_in[30];
    const float* miW1      = (const float*)d_in[31];
    const float* mib1      = (const float*)d_in[32];
    const float* miW2      = (const float*)d_in[33];
    const float* mib2      = (const float*)d_in[34];
    const float* meW1      = (const float*)d_in[35];
    const float* meb1      = (const float*)d_in[36];
    const float* meW2      = (const float*)d_in[37];
    const float* meb2      = (const float*)d_in[38];
    float* out = (float*)d_out;

    char* ws = (char*)d_ws;
    size_t o = 0;
    auto alloc = [&](size_t bytes) { size_t r = o; o += (bytes + 255) & ~(size_t)255; return r; };
    u16*   kkp   = (u16*)  (ws + alloc((size_t)kB * kN * 128 * 2));
    u16*   vvp   = (u16*)  (ws + alloc((size_t)kB * kN * 128 * 2));
    float* Wcomb = (float*)(ws + alloc(128 * 256 * 4));
    float* vpart = (float*)(ws + alloc((size_t)4096 * 128 * 4));
    float* vvsum = (float*)(ws + alloc(8192 * 4));
    float* pbuf  = (float*)(ws + alloc(4096 * 4));
    float* pT    = (float*)(ws + alloc(4096 * 4));
    float* sext  = (float*)(ws + alloc(32768 * 4));
    float* lpi   = (float*)(ws + alloc(32768 * 4));
    float* sint  = (float*)(ws + alloc(32768 * 4));
    float* q     = (float*)(ws + alloc(65536 * 4));
    float* pu    = (float*)(ws + alloc((size_t)1024 * 1024 * 4));
    float* pcs   = (float*)(ws + alloc(8192 * 4));

    kinit<<<128, 256, 0, stream>>>(ext_mu, ext_ls, int_mu, int_ls, ext_noise, int_noise, sext, lpi);
    kprep<<<1, 256, 0, stream>>>(Wk, Wv, protos, Wp, ln_p_g, ln_p_b, Wcomb, pbuf, pT);
    kmain<<<4096, 256, 0, stream>>>(inputs, Wcomb, ln_in_g, ln_in_b, kkp, vvp, vpart);
    kvvsum<<<32, 256, 0, stream>>>(vpart, vvsum);

    for (int i = 0; i < 3; ++i) {
        kslots<<<512, 128, 0, stream>>>(lpi, gumbel + (size_t)i * 32768, taup, pbuf,
                                        slots_bck, sext, Wq, sint, q);
        kattn<<<1024, 256, 0, stream>>>(kkp, vvp, q, out + 57344, pu, pcs);
        kupdate<<<512, 256, 0, stream>>>(pu, pcs, vvsum, sint, sext, lpi,
                                         giWih, giWhh, gibih, gibhh,
                                         geWih, geWhh, gebih, gebhh,
                                         miW1, mib1, miW2, mib2,
                                         meW1, meb1, meW2, meb2,
                                         ln_mi_g, ln_mi_b, ln_me_g, ln_me_b,
                                         pT, out, (i == 2) ? 1 : 0);
    }
}

// Round 2
// 316.565 us; speedup vs baseline: 1.5826x; 1.5826x over previous
//
#include <hip/hip_runtime.h>
#include <stdint.h>

typedef unsigned short u16;
#define DEVFN static __device__ __forceinline__

typedef __attribute__((ext_vector_type(8))) short bf16x8;
typedef __attribute__((ext_vector_type(4))) float f32x4;

constexpr int   kB   = 64;
constexpr int   kN   = 4096;
constexpr float kEPS = 1e-8f;
constexpr float kLNE = 1e-5f;
constexpr float kKSC = 0.08838834764831845f;  // SLOT^-0.5
constexpr float kISC = 0.125f;                 // I^-0.5

DEVFN float bf2f(uint32_t u) { union { uint32_t u; float f; } x; x.u = u << 16; return x.f; }
DEVFN u16 f2bf(float f) {
    union { float f; uint32_t u; } x; x.f = f;
    uint32_t r = (x.u + 0x7fffu + ((x.u >> 16) & 1u)) >> 16;
    return (u16)r;
}
DEVFN void unpack8(uint4 p, float* d) {
    d[0] = bf2f(p.x & 0xffffu); d[1] = bf2f(p.x >> 16);
    d[2] = bf2f(p.y & 0xffffu); d[3] = bf2f(p.y >> 16);
    d[4] = bf2f(p.z & 0xffffu); d[5] = bf2f(p.z >> 16);
    d[6] = bf2f(p.w & 0xffffu); d[7] = bf2f(p.w >> 16);
}
DEVFN float sigf(float x) { return 1.0f / (1.0f + __expf(-x)); }

// ---------------- A0: init slots_ext / logits_pi ----------------
__global__ void kinit(const float* __restrict__ ext_mu, const float* __restrict__ ext_ls,
                      const float* __restrict__ int_mu, const float* __restrict__ int_ls,
                      const float* __restrict__ ext_noise, const float* __restrict__ int_noise,
                      float* __restrict__ sext, float* __restrict__ lpi)
{
    int t = blockIdx.x * 256 + threadIdx.x;  // 32768 threads
    int e = t & 63;
    sext[t] = ext_mu[e] + __expf(ext_ls[e]) * ext_noise[t];
    lpi[t]  = int_mu[e] + __expf(int_ls[e]) * int_noise[t];
}

// ---------------- A2w: WT_bf16[c][k] = (c<128 ? Wk[k][c]*scale : Wv[k][c-128]) ----------------
__global__ void kwprep(const float* __restrict__ Wk, const float* __restrict__ Wv,
                       u16* __restrict__ WT)
{
    int idx = blockIdx.x * 256 + threadIdx.x;   // 32768
    int k = idx >> 8, c = idx & 255;
    float v = (c < 128) ? Wk[k * 128 + c] * kKSC : Wv[k * 128 + (c - 128)];
    WT[(size_t)c * 128 + k] = f2bf(v);
}

// ---------------- A2: p = LN(protos)@Wp; pT ----------------
__global__ void kprep(const float* __restrict__ protos, const float* __restrict__ Wp,
                      const float* __restrict__ lpg, const float* __restrict__ lpb,
                      float* __restrict__ p, float* __restrict__ pT)
{
    __shared__ float pl[64][65];
    __shared__ float mS[64], sS[64];
    int t = threadIdx.x;  // 256
    for (int idx = t; idx < 64 * 64; idx += 256) pl[idx >> 6][idx & 63] = protos[idx];
    __syncthreads();
    if (t < 64) {
        float sm = 0.f, sq = 0.f;
        for (int k = 0; k < 64; ++k) { float v = pl[t][k]; sm += v; sq += v * v; }
        float m = sm * (1.0f / 64.0f);
        float var = sq * (1.0f / 64.0f) - m * m;
        mS[t] = m; sS[t] = rsqrtf(var + kLNE);
    }
    __syncthreads();
    for (int idx = t; idx < 64 * 64; idx += 256) {
        int r = idx >> 6, c = idx & 63;
        pl[r][c] = (pl[r][c] - mS[r]) * sS[r] * lpg[c] + lpb[c];
    }
    __syncthreads();
    for (int idx = t; idx < 64 * 64; idx += 256) {
        int r = idx >> 6, c = idx & 63;
        float acc = 0.f;
        for (int k = 0; k < 64; ++k) acc += pl[r][k] * Wp[k * 64 + c];
        p[r * 64 + c] = acc;
        pT[c * 64 + r] = acc;
    }
}

// ---------------- A1: x=LN(inputs) (bf16); kk|vv = x@[Wk*s|Wv] via MFMA; vvsum partials ----
// 4096 blocks x 256 threads; 64 rows/block. LDS: 16KB swizzled bf16 A-tile.
__global__ __launch_bounds__(256) void kmain(const float* __restrict__ inputs,
                                             const u16* __restrict__ WT,
                                             const float* __restrict__ lng, const float* __restrict__ lnb,
                                             u16* __restrict__ kk, u16* __restrict__ vv,
                                             float* __restrict__ vpart)
{
    __shared__ u16 At[64 * 128];   // [row][128 bf16], 16B-chunk XOR swizzle by row&7
    const int t = threadIdx.x;
    const int blk = blockIdx.x;           // 4096
    const int b = blk >> 6;
    const int n0 = (blk & 63) * 64;
    const float* inp = inputs + ((size_t)(b * kN + n0)) * 128;

    // coalesced load: thread t holds float4 #(t + j*256): row=(t>>5)+8j, col4=t&31
    float4 xv[8];
    #pragma unroll
    for (int j = 0; j < 8; ++j) xv[j] = ((const float4*)inp)[t + j * 256];

    float s[8], qq[8];
    #pragma unroll
    for (int j = 0; j < 8; ++j) {
        s[j]  = xv[j].x + xv[j].y + xv[j].z + xv[j].w;
        qq[j] = xv[j].x * xv[j].x + xv[j].y * xv[j].y + xv[j].z * xv[j].z + xv[j].w * xv[j].w;
    }
    #pragma unroll
    for (int d = 16; d >= 1; d >>= 1) {
        #pragma unroll
        for (int j = 0; j < 8; ++j) {
            s[j]  += __shfl_xor(s[j], d);
            qq[j] += __shfl_xor(qq[j], d);
        }
    }
    const int col4 = t & 31;
    const float4 g4 = ((const float4*)lng)[col4];
    const float4 b4 = ((const float4*)lnb)[col4];
    #pragma unroll
    for (int j = 0; j < 8; ++j) {
        const int row = (t >> 5) + 8 * j;
        const float m  = s[j] * (1.0f / 128.0f);
        const float var = qq[j] * (1.0f / 128.0f) - m * m;
        const float sc = rsqrtf(var + kLNE);
        const float a0 = (xv[j].x - m) * sc * g4.x + b4.x;
        const float a1 = (xv[j].y - m) * sc * g4.y + b4.y;
        const float a2 = (xv[j].z - m) * sc * g4.z + b4.z;
        const float a3 = (xv[j].w - m) * sc * g4.w + b4.w;
        uint32_t p0 = (uint32_t)f2bf(a0) | ((uint32_t)f2bf(a1) << 16);
        uint32_t p1 = (uint32_t)f2bf(a2) | ((uint32_t)f2bf(a3) << 16);
        const int byteoff = row * 256 + (((col4 >> 1) ^ (row & 7)) << 4) + ((col4 & 1) << 3);
        *(uint2*)((char*)At + byteoff) = make_uint2(p0, p1);
    }
    __syncthreads();

    const int w   = t >> 6;       // wave 0..3 -> output cols [64w, 64w+64)
    const int l   = t & 63;
    const int lg  = l >> 4;       // k-group
    const int lr  = l & 15;       // row (A) / col (B) within tile
    const int wc0 = w * 64;

    f32x4 acc[4][4];
    #pragma unroll
    for (int m = 0; m < 4; ++m)
        #pragma unroll
        for (int n = 0; n < 4; ++n) acc[m][n] = (f32x4){0.f, 0.f, 0.f, 0.f};

    #pragma unroll
    for (int ks = 0; ks < 4; ++ks) {
        bf16x8 afr[4];
        #pragma unroll
        for (int m = 0; m < 4; ++m) {
            const int row = 16 * m + lr;
            const int chunk = (ks * 4 + lg) ^ (row & 7);
            afr[m] = *(const bf16x8*)((const char*)At + row * 256 + chunk * 16);
        }
        #pragma unroll
        for (int n = 0; n < 4; ++n) {
            const int col = wc0 + 16 * n + lr;
            bf16x8 bfr = *(const bf16x8*)(WT + (size_t)col * 128 + ks * 32 + lg * 8);
            #pragma unroll
            for (int m = 0; m < 4; ++m)
                acc[m][n] = __builtin_amdgcn_mfma_f32_16x16x32_bf16(afr[m], bfr, acc[m][n], 0, 0, 0);
        }
    }

    // store C: lane l reg r of tile(m,n) = C[16m + lg*4 + r][wc0 + 16n + lr]
    #pragma unroll
    for (int n = 0; n < 4; ++n) {
        const int colg = wc0 + 16 * n + lr;
        u16* basep = (colg < 128) ? kk : vv;
        const int colo = colg & 127;
        #pragma unroll
        for (int m = 0; m < 4; ++m) {
            #pragma unroll
            for (int r = 0; r < 4; ++r) {
                const int row = n0 + 16 * m + lg * 4 + r;
                basep[((size_t)(b * kN) + row) * 128 + colo] = f2bf(acc[m][n][r]);
            }
        }
    }
    // vvsum partials (vv half: waves 2,3)
    if (w >= 2) {
        #pragma unroll
        for (int n = 0; n < 4; ++n) {
            float sv = 0.f;
            #pragma unroll
            for (int m = 0; m < 4; ++m)
                #pragma unroll
                for (int r = 0; r < 4; ++r) sv += acc[m][n][r];
            sv += __shfl_xor(sv, 16);
            sv += __shfl_xor(sv, 32);
            if (lg == 0) vpart[(size_t)blk * 128 + (wc0 - 128) + 16 * n + lr] = sv;
        }
    }
}

// ---------------- A3: reduce vvsum partials ----------------
__global__ void kvvsum(const float* __restrict__ part, float* __restrict__ vvsum)
{
    int t = blockIdx.x * 256 + threadIdx.x;  // 8192
    int b = t >> 7, c = t & 127;
    float s = 0.f;
    const float* pp = part + (size_t)b * 64 * 128 + c;
    for (int nb = 0; nb < 64; ++nb) s += pp[nb * 128];
    vvsum[t] = s;
}

// ---------------- K1: pi softmax, slots_int, slots build, q ----------------
__global__ void kslots(const float* __restrict__ lpi, const float* __restrict__ gum,
                       const void* __restrict__ taup,
                       const float* __restrict__ p,
                       const float* __restrict__ sbck, const float* __restrict__ sext,
                       const float* __restrict__ Wq,
                       float* __restrict__ sint, float* __restrict__ q)
{
    __shared__ float piL[64];
    __shared__ float sv[128];
    const int bs = blockIdx.x;     // 512
    const int b = bs >> 3, s = bs & 7;
    const int t = threadIdx.x;     // 128
    float inv_tau = 1.0f;
    {
        int iv = *(const int*)taup;
        if (iv > 0 && iv < 1000000) inv_tau = 1.0f / (float)iv;
        else {
            float fv = *(const float*)taup;
            if (fv > 1e-6f && fv < 1e6f) inv_tau = 1.0f / fv;
        }
    }
    if (t < 64) {
        float l = (lpi[bs * 64 + t] + gum[bs * 64 + t]) * inv_tau;
        float m = l;
        #pragma unroll
        for (int d = 32; d >= 1; d >>= 1) m = fmaxf(m, __shfl_xor(m, d));
        float e = __expf(l - m);
        float sm = e;
        #pragma unroll
        for (int d = 32; d >= 1; d >>= 1) sm += __shfl_xor(sm, d);
        piL[t] = e / sm;
    }
    __syncthreads();
    if (t < 64) {
        float acc = 0.f;
        for (int c = 0; c < 64; ++c) acc += piL[c] * p[c * 64 + t];
        sint[bs * 64 + t] = acc;
        if (s == 0) {
            sv[t]      = sbck[b * 128 + t];
            sv[64 + t] = sbck[b * 128 + 64 + t];
        } else {
            sv[t]      = acc;
            sv[64 + t] = sext[bs * 64 + t];
        }
    }
    __syncthreads();
    {
        float acc = 0.f;
        for (int k = 0; k < 128; ++k) acc += sv[k] * Wq[k * 128 + t];
        q[bs * 128 + t] = acc;
    }
}

// ---------------- K2: attention pass ----------------
__global__ __launch_bounds__(256) void kattn(const u16* __restrict__ kk, const u16* __restrict__ vv,
                                             const float* __restrict__ q,
                                             float* __restrict__ attn_out,
                                             float* __restrict__ pu, float* __restrict__ pcs,
                                             const int wvis)
{
    __shared__ float qL[8][132];
    __shared__ float kkL[32][132];
    __shared__ float vvL[32][132];
    __shared__ float aL[32 * 8];
    const int t = threadIdx.x;
    const int blk = blockIdx.x;     // 1024
    const int b = blk >> 4;
    const int nb = blk & 15;        // 256 rows per block
    {
        int idx = t * 4;
        float4 v = *((const float4*)(q + (size_t)b * 1024 + idx));
        *((float4*)&qL[idx >> 7][idx & 127]) = v;
    }
    const int r8 = t >> 3, sl = t & 7;
    const int s2 = t >> 5, dg = t & 31;
    float acc0 = 0.f, acc1 = 0.f, acc2 = 0.f, acc3 = 0.f, cs = 0.f;
    __syncthreads();
    for (int ch = 0; ch < 8; ++ch) {
        const int nbase = nb * 256 + ch * 32;
        const u16* kp = kk + ((size_t)(b * kN + nbase)) * 128;
        const u16* vp = vv + ((size_t)(b * kN + nbase)) * 128;
        #pragma unroll
        for (int rnd = 0; rnd < 2; ++rnd) {
            const int flat = (t + rnd * 256) * 8;
            const int rr = flat >> 7, c0 = flat & 127;
            uint4 pk = *((const uint4*)(kp + flat));
            uint4 pv = *((const uint4*)(vp + flat));
            float fk[8], fvv[8];
            unpack8(pk, fk); unpack8(pv, fvv);
            *((float4*)&kkL[rr][c0])     = make_float4(fk[0], fk[1], fk[2], fk[3]);
            *((float4*)&kkL[rr][c0 + 4]) = make_float4(fk[4], fk[5], fk[6], fk[7]);
            *((float4*)&vvL[rr][c0])     = make_float4(fvv[0], fvv[1], fvv[2], fvv[3]);
            *((float4*)&vvL[rr][c0 + 4]) = make_float4(fvv[4], fvv[5], fvv[6], fvv[7]);
        }
        __syncthreads();
        float lg = 0.f;
        {
            const float4* kr = (const float4*)&kkL[r8][0];
            const float4* qr = (const float4*)&qL[sl][0];
            #pragma unroll 8
            for (int k4 = 0; k4 < 32; ++k4) {
                float4 kx = kr[k4], qx = qr[k4];
                lg = fmaf(kx.x, qx.x, lg); lg = fmaf(kx.y, qx.y, lg);
                lg = fmaf(kx.z, qx.z, lg); lg = fmaf(kx.w, qx.w, lg);
            }
        }
        float m = lg;
        m = fmaxf(m, __shfl_xor(m, 1)); m = fmaxf(m, __shfl_xor(m, 2)); m = fmaxf(m, __shfl_xor(m, 4));
        float e = __expf(lg - m);
        float sm = e;
        sm += __shfl_xor(sm, 1); sm += __shfl_xor(sm, 2); sm += __shfl_xor(sm, 4);
        float av = e / sm;
        if (wvis) attn_out[((size_t)(b * kN + nbase + r8)) * 8 + sl] = av;
        aL[r8 * 8 + sl] = av;
        __syncthreads();
        #pragma unroll 4
        for (int rr = 0; rr < 32; ++rr) {
            float aw = aL[rr * 8 + s2];
            float4 v = *((const float4*)&vvL[rr][dg * 4]);
            acc0 = fmaf(aw, v.x, acc0); acc1 = fmaf(aw, v.y, acc1);
            acc2 = fmaf(aw, v.z, acc2); acc3 = fmaf(aw, v.w, acc3);
            cs += aw;
        }
        __syncthreads();
    }
    *((float4*)(pu + (size_t)blk * 1024 + s2 * 128 + dg * 4)) = make_float4(acc0, acc1, acc2, acc3);
    if (dg == 0) pcs[blk * 8 + s2] = cs;
}

// ---------------- K3: updates, GRUs, MLPs, new logits; final outputs ----------------
__global__ __launch_bounds__(256) void kupdate(
    const float* __restrict__ pu, const float* __restrict__ pcs,
    const float* __restrict__ vvsum, const float* __restrict__ sint,
    float* __restrict__ sext, float* __restrict__ lpi,
    const float* __restrict__ giWih, const float* __restrict__ giWhh,
    const float* __restrict__ gibih, const float* __restrict__ gibhh,
    const float* __restrict__ geWih, const float* __restrict__ geWhh,
    const float* __restrict__ gebih, const float* __restrict__ gebhh,
    const float* __restrict__ miW1, const float* __restrict__ mib1,
    const float* __restrict__ miW2, const float* __restrict__ mib2,
    const float* __restrict__ meW1, const float* __restrict__ meb1,
    const float* __restrict__ meW2, const float* __restrict__ meb2,
    const float* __restrict__ lmig, const float* __restrict__ lmib,
    const float* __restrict__ lmeg, const float* __restrict__ lmeb,
    const float* __restrict__ pT, float* __restrict__ out, const int last)
{
    __shared__ float uL[128], hA[64], hB[64];
    __shared__ float g1[192], g2[192];
    __shared__ float tmp[256];
    __shared__ float outE[64], outI[64];
    const int bs = blockIdx.x;   // 512
    const int b = bs >> 3, s = bs & 7;
    const int t = threadIdx.x;   // 256

    if (t < 128) {
        float num = 0.f;
        for (int nb = 0; nb < 16; ++nb) num += pu[((size_t)((b * 16 + nb) * 8 + s)) * 128 + t];
        float den = 4096.0f * kEPS;
        for (int nb = 0; nb < 16; ++nb) den += pcs[(b * 16 + nb) * 8 + s];
        uL[t] = (num + kEPS * vvsum[b * 128 + t]) / den;
    } else if (t < 192) {
        hA[t - 128] = sext[bs * 64 + (t - 128)];
    } else {
        hB[t - 192] = sint[bs * 64 + (t - 192)];
    }
    __syncthreads();
    if (t < 192) {
        float a = gebih[t], bb = gebhh[t];
        for (int k = 0; k < 64; ++k) {
            a  = fmaf(uL[64 + k], geWih[k * 192 + t], a);
            bb = fmaf(hA[k],      geWhh[k * 192 + t], bb);
        }
        g1[t] = a; g2[t] = bb;
    }
    __syncthreads();
    if (t < 64) {
        float r = sigf(g1[t] + g2[t]);
        float z = sigf(g1[64 + t] + g2[64 + t]);
        float nn = tanhf(g1[128 + t] + r * g2[128 + t]);
        outE[t] = (1.0f - z) * nn + z * hA[t];
    }
    __syncthreads();
    if (t < 192) {
        float a = gibih[t], bb = gibhh[t];
        for (int k = 0; k < 64; ++k) {
            a  = fmaf(uL[k], giWih[k * 192 + t], a);
            bb = fmaf(hB[k], giWhh[k * 192 + t], bb);
        }
        g1[t] = a; g2[t] = bb;
    }
    __syncthreads();
    if (t < 64) {
        float r = sigf(g1[t] + g2[t]);
        float z = sigf(g1[64 + t] + g2[64 + t]);
        float nn = tanhf(g1[128 + t] + r * g2[128 + t]);
        outI[t] = (1.0f - z) * nn + z * hB[t];
    }
    __syncthreads();
    if (!last) {
        if (t < 64) {
            float v = outE[t];
            float sm = v, sq = v * v;
            #pragma unroll
            for (int d = 32; d >= 1; d >>= 1) { sm += __shfl_xor(sm, d); sq += __shfl_xor(sq, d); }
            float m = sm * (1.0f / 64.0f), var = sq * (1.0f / 64.0f) - m * m;
            g1[t] = (v - m) * rsqrtf(var + kLNE) * lmeg[t] + lmeb[t];
        }
        __syncthreads();
        {
            float a = meb1[t];
            for (int k = 0; k < 64; ++k) a = fmaf(g1[k], meW1[k * 256 + t], a);
            tmp[t] = fmaxf(a, 0.0f);
        }
        __syncthreads();
        if (t < 64) {
            float o = meb2[t];
            for (int j = 0; j < 256; ++j) o = fmaf(tmp[j], meW2[j * 64 + t], o);
            outE[t] += o;
        }
        __syncthreads();
        if (t < 64) {
            float v = outI[t];
            float sm = v, sq = v * v;
            #pragma unroll
            for (int d = 32; d >= 1; d >>= 1) { sm += __shfl_xor(sm, d); sq += __shfl_xor(sq, d); }
            float m = sm * (1.0f / 64.0f), var = sq * (1.0f / 64.0f) - m * m;
            g1[t] = (v - m) * rsqrtf(var + kLNE) * lmig[t] + lmib[t];
        }
        __syncthreads();
        {
            float a = mib1[t];
            for (int k = 0; k < 64; ++k) a = fmaf(g1[k], miW1[k * 256 + t], a);
            tmp[t] = fmaxf(a, 0.0f);
        }
        __syncthreads();
        if (t < 64) {
            float o = mib2[t];
            for (int j = 0; j < 256; ++j) o = fmaf(tmp[j], miW2[j * 64 + t], o);
            outI[t] += o;
        }
        __syncthreads();
    }
    if (t < 64) {
        float lg = 0.f;
        for (int k = 0; k < 64; ++k) lg = fmaf(outI[k], pT[k * 64 + t], lg);
        lg *= kISC;
        lpi[bs * 64 + t] = lg;
        if (last && s > 0) out[28672 + (b * 7 + (s - 1)) * 64 + t] = lg;
    } else if (t < 128) {
        int c = t - 64;
        float v = outE[c];
        sext[bs * 64 + c] = v;
        if (last && s > 0) out[(b * 7 + (s - 1)) * 64 + c] = v;
    }
}

extern "C" void kernel_launch(void* const* d_in, const int* in_sizes, int n_in,
                              void* d_out, int out_size, void* d_ws, size_t ws_size,
                              hipStream_t stream)
{
    (void)in_sizes; (void)n_in; (void)out_size; (void)ws_size;
    const float* slots_bck = (const float*)d_in[0];
    const float* inputs    = (const float*)d_in[1];
    const float* protos    = (const float*)d_in[2];
    const float* ext_noise = (const float*)d_in[3];
    const float* int_noise = (const float*)d_in[4];
    const float* gumbel    = (const float*)d_in[5];
    const void*  taup      = d_in[6];
    const float* ext_mu    = (const float*)d_in[7];
    const float* ext_ls    = (const float*)d_in[8];
    const float* int_mu    = (const float*)d_in[9];
    const float* int_ls    = (const float*)d_in[10];
    const float* ln_in_g   = (const float*)d_in[11];
    const float* ln_in_b   = (const float*)d_in[12];
    const float* ln_p_g    = (const float*)d_in[13];
    const float* ln_p_b    = (const float*)d_in[14];
    const float* ln_mi_g   = (const float*)d_in[15];
    const float* ln_mi_b   = (const float*)d_in[16];
    const float* ln_me_g   = (const float*)d_in[17];
    const float* ln_me_b   = (const float*)d_in[18];
    const float* Wq        = (const float*)d_in[19];
    const float* Wk        = (const float*)d_in[20];
    const float* Wv        = (const float*)d_in[21];
    const float* Wp        = (const float*)d_in[22];
    const float* giWih     = (const float*)d_in[23];
    const float* giWhh     = (const float*)d_in[24];
    const float* gibih     = (const float*)d_in[25];
    const float* gibhh     = (const float*)d_in[26];
    const float* geWih     = (const float*)d_in[27];
    const float* geWhh     = (const float*)d_in[28];
    const float* gebih     = (const float*)d_in[29];
    const float* gebhh     = (const float*)d_in[30];
    const float* miW1      = (const float*)d_in[31];
    const float* mib1      = (const float*)d_in[32];
    const float* miW2      = (const float*)d_in[33];
    const float* mib2      = (const float*)d_in[34];
    const float* meW1      = (const float*)d_in[35];
    const float* meb1      = (const float*)d_in[36];
    const float* meW2      = (const float*)d_in[37];
    const float* meb2      = (const float*)d_in[38];
    float* out = (float*)d_out;

    char* ws = (char*)d_ws;
    size_t o = 0;
    auto alloc = [&](size_t bytes) { size_t r = o; o += (bytes + 255) & ~(size_t)255; return r; };
    u16*   kkp   = (u16*)  (ws + alloc((size_t)kB * kN * 128 * 2));
    u16*   vvp   = (u16*)  (ws + alloc((size_t)kB * kN * 128 * 2));
    u16*   WT    = (u16*)  (ws + alloc(256 * 128 * 2));
    float* vpart = (float*)(ws + alloc((size_t)4096 * 128 * 4));
    float* vvsum = (float*)(ws + alloc(8192 * 4));
    float* pbuf  = (float*)(ws + alloc(4096 * 4));
    float* pT    = (float*)(ws + alloc(4096 * 4));
    float* sext  = (float*)(ws + alloc(32768 * 4));
    float* lpi   = (float*)(ws + alloc(32768 * 4));
    float* sint  = (float*)(ws + alloc(32768 * 4));
    float* q     = (float*)(ws + alloc(65536 * 4));
    float* pu    = (float*)(ws + alloc((size_t)1024 * 1024 * 4));
    float* pcs   = (float*)(ws + alloc(8192 * 4));

    kinit<<<128, 256, 0, stream>>>(ext_mu, ext_ls, int_mu, int_ls, ext_noise, int_noise, sext, lpi);
    kwprep<<<128, 256, 0, stream>>>(Wk, Wv, WT);
    kprep<<<1, 256, 0, stream>>>(protos, Wp, ln_p_g, ln_p_b, pbuf, pT);
    kmain<<<4096, 256, 0, stream>>>(inputs, WT, ln_in_g, ln_in_b, kkp, vvp, vpart);
    kvvsum<<<32, 256, 0, stream>>>(vpart, vvsum);

    for (int i = 0; i < 3; ++i) {
        kslots<<<512, 128, 0, stream>>>(lpi, gumbel + (size_t)i * 32768, taup, pbuf,
                                        slots_bck, sext, Wq, sint, q);
        kattn<<<1024, 256, 0, stream>>>(kkp, vvp, q, out + 57344, pu, pcs, (i == 2) ? 1 : 0);
        kupdate<<<512, 256, 0, stream>>>(pu, pcs, vvsum, sint, sext, lpi,
                                         giWih, giWhh, gibih, gibhh,
                                         geWih, geWhh, gebih, gebhh,
                                         miW1, mib1, miW2, mib2,
                                         meW1, meb1, meW2, meb2,
                                         ln_mi_g, ln_mi_b, ln_me_g, ln_me_b,
                                         pT, out, (i == 2) ? 1 : 0);
    }
}